// Round 2
// baseline (258.246 us; speedup 1.0000x reference)
//
#include <hip/hip_runtime.h>
#include <math.h>

#define T_ 128
#define B_ 8
#define C_ 25000
#define W_ 4
#define NROWS (T_ * B_)   // 1024

// Tie-exact comparator: value desc, index asc (matches lax.top_k tie rule).
__device__ __forceinline__ bool better(float av, int ai, float bv, int bi) {
  return (av > bv) || (av == bv && ai < bi);
}

// ---------------------------------------------------------------------------
// Kernel A: per row (t,b): top-4 (value,index) of raw logits (exact f32 bit
// comparisons), online-softmax denominator, and f64 p_k = exp(v_k - v_0)/den,
// lp_k = log(p_k). One block of 256 threads per row.
// ---------------------------------------------------------------------------
__global__ __launch_bounds__(256) void rowstats(
    const float* __restrict__ logits,
    float* __restrict__ r_v, int* __restrict__ r_i,
    double* __restrict__ r_p, double* __restrict__ r_lp) {
  const int row = blockIdx.x;
  const float4* __restrict__ x4 =
      reinterpret_cast<const float4*>(logits + (size_t)row * C_);
  const int tid = threadIdx.x;

  float tv[4] = {-INFINITY, -INFINITY, -INFINITY, -INFINITY};
  int ti[4] = {0x7fffffff, 0x7fffffff, 0x7fffffff, 0x7fffffff};
  float m = -INFINITY, s = 0.0f;

  for (int i = tid; i < C_ / 4; i += 256) {
    float4 q = x4[i];
    float vals[4] = {q.x, q.y, q.z, q.w};
#pragma unroll
    for (int j = 0; j < 4; ++j) {
      float val = vals[j];
      int gi = 4 * i + j;
      // online softmax denominator (relative to running max)
      if (val > m) {
        s = s * expf(m - val) + 1.0f;
        m = val;
      } else {
        s += expf(val - m);
      }
      // top-4 insertion (value desc, index asc on ties)
      float cv = val; int ci2 = gi;
#pragma unroll
      for (int k = 0; k < 4; ++k) {
        if (better(cv, ci2, tv[k], ti[k])) {
          float t0 = tv[k]; int t1 = ti[k];
          tv[k] = cv; ti[k] = ci2;
          cv = t0; ci2 = t1;
        }
      }
    }
  }

  __shared__ float sv[256][4];
  __shared__ int si[256][4];
  __shared__ float smm[256], sms[256];
#pragma unroll
  for (int k = 0; k < 4; ++k) { sv[tid][k] = tv[k]; si[tid][k] = ti[k]; }
  smm[tid] = m; sms[tid] = s;
  __syncthreads();

  for (int off = 128; off > 0; off >>= 1) {
    if (tid < off) {
      // merge (m,s)
      float m1 = smm[tid], s1 = sms[tid];
      float m2 = smm[tid + off], s2 = sms[tid + off];
      if (m2 > m1) { s1 = s1 * expf(m1 - m2) + s2; m1 = m2; }
      else { s1 = s1 + s2 * expf(m2 - m1); }
      smm[tid] = m1; sms[tid] = s1;
      // merge two sorted-4 lists (2-pointer; at pick k, pa+pb==k<=3, safe)
      float a0[4], ov[4]; int a1[4], oi[4];
#pragma unroll
      for (int k = 0; k < 4; ++k) { a0[k] = sv[tid][k]; a1[k] = si[tid][k]; }
      int pa = 0, pb = 0;
#pragma unroll
      for (int k = 0; k < 4; ++k) {
        float bv_ = sv[tid + off][pb]; int bi_ = si[tid + off][pb];
        if (better(a0[pa], a1[pa], bv_, bi_)) { ov[k] = a0[pa]; oi[k] = a1[pa]; ++pa; }
        else { ov[k] = bv_; oi[k] = bi_; ++pb; }
      }
#pragma unroll
      for (int k = 0; k < 4; ++k) { sv[tid][k] = ov[k]; si[tid][k] = oi[k]; }
    }
    __syncthreads();
  }

  if (tid == 0) {
    double den = (double)sms[0];
    double v0 = (double)sv[0][0];
#pragma unroll
    for (int k = 0; k < 4; ++k) {
      r_v[row * 4 + k] = sv[0][k];
      r_i[row * 4 + k] = si[0][k];
      double p = exp((double)sv[0][k] - v0) / den;
      r_p[row * 4 + k] = p;
      r_lp[row * 4 + k] = log(p);
    }
  }
}

// ---------------------------------------------------------------------------
// Kernel B: faithful beam recursion per batch (one block per batch; thread 0
// runs the serial 128-step recursion; all threads write outputs).
// Handles exact ties/forks: candidate order = (value-bits desc, parent asc,
// char asc) == flattened-index tie rule of lax.top_k; stable re-sort by logs;
// stable final sort by f32 scores; backpointer reconstruction.
// ---------------------------------------------------------------------------
__global__ __launch_bounds__(64) void beam_sim(
    const float* __restrict__ r_v, const int* __restrict__ r_i,
    const double* __restrict__ r_p, const double* __restrict__ r_lp,
    float* __restrict__ out) {
  const int b = blockIdx.x;
  const int tid = threadIdx.x;

  __shared__ int P[T_][W_];        // parent (post-resort) per step
  __shared__ int Ch[T_][W_];       // raw char per step
  __shared__ int seq[W_][T_ + 1];
  __shared__ double sh_scores[W_], sh_logs[W_];

  if (tid == 0) {
    double logs[4] = {0.0, 0.0, 0.0, 0.0};
    double scor[4] = {0.0, 0.0, 0.0, 0.0};
    int nw = 1;  // only beam 0 active at t=0

    for (int t = 0; t < T_; ++t) {
      int row = t * B_ + b;
      float v[4]; int ci[4]; double pk[4], lpk[4];
#pragma unroll
      for (int k = 0; k < 4; ++k) {
        v[k] = r_v[row * 4 + k];
        ci[k] = r_i[row * 4 + k];
        pk[k] = r_p[row * 4 + k];
        lpk[k] = r_lp[row * 4 + k];
      }

      // global top-4 over (parent, char) candidates.
      // groups of bit-equal values; within a tie group order = (w asc, c asc)
      int sw[4], sc[4], sk[4]; int ns = 0;
      int k = 0;
      while (ns < 4 && k < 4) {
        int k2 = k;
        while (k2 + 1 < 4 &&
               __float_as_uint(v[k2 + 1]) == __float_as_uint(v[k])) ++k2;
        for (int w = 0; w < nw && ns < 4; ++w)
          for (int kk = k; kk <= k2 && ns < 4; ++kk) {
            sw[ns] = w; sc[ns] = ci[kk]; sk[ns] = kk; ++ns;
          }
        k = k2 + 1;
      }

      // cumulative logs of the 4 children
      double nl[4];
      for (int j = 0; j < 4; ++j) nl[j] = logs[sw[j]] + lpk[sk[j]];

      // stable argsort desc by nl (equal keys keep slot order)
      int ord[4] = {0, 1, 2, 3};
      for (int a = 1; a < 4; ++a) {
        int o = ord[a]; int bb = a;
        while (bb > 0 && nl[ord[bb - 1]] < nl[o]) { ord[bb] = ord[bb - 1]; --bb; }
        ord[bb] = o;
      }

      double tl[4], ts[4];
      for (int j = 0; j < 4; ++j) {
        tl[j] = nl[ord[j]];
        ts[j] = pk[sk[ord[j]]];
        P[t][j] = sw[ord[j]];
        Ch[t][j] = sc[ord[j]];
      }
      for (int j = 0; j < 4; ++j) { logs[j] = tl[j]; scor[j] = ts[j]; }
      nw = 4;
    }

    // final stable sort by f32-cast scores, desc (matches argsort(-scores))
    float sf[4];
    for (int j = 0; j < 4; ++j) sf[j] = (float)scor[j];
    int ford[4] = {0, 1, 2, 3};
    for (int a = 1; a < 4; ++a) {
      int o = ford[a]; int bb = a;
      while (bb > 0 && sf[ford[bb - 1]] < sf[o]) { ford[bb] = ford[bb - 1]; --bb; }
      ford[bb] = o;
    }

    for (int w = 0; w < 4; ++w) {
      int j = ford[w];
      sh_scores[w] = scor[j];
      sh_logs[w] = logs[j];
      for (int t = T_ - 1; t >= 0; --t) { seq[w][t + 1] = Ch[t][j]; j = P[t][j]; }
      seq[w][0] = 0;  // BLANK
    }
  }
  __syncthreads();

  // write outputs: seqs [B][W][T+1], then scores [B][W], then logs [B][W]
  for (int e = tid; e < W_ * (T_ + 1); e += 64) {
    int w = e / (T_ + 1), p = e % (T_ + 1);
    int c = seq[w][p];
    if (c == 1) c = 0;  // EOS -> BLANK
    out[(size_t)(b * W_ + w) * (T_ + 1) + p] = (float)c;
  }
  if (tid < W_) {
    out[B_ * W_ * (T_ + 1) + b * W_ + tid] = (float)sh_scores[tid];
    out[B_ * W_ * (T_ + 1) + B_ * W_ + b * W_ + tid] = (float)sh_logs[tid];
  }
}

// ---------------------------------------------------------------------------
extern "C" void kernel_launch(void* const* d_in, const int* in_sizes, int n_in,
                              void* d_out, int out_size, void* d_ws,
                              size_t ws_size, hipStream_t stream) {
  const float* logits = (const float*)d_in[0];
  // d_in[1] = seq_len (all == T): unused by the reference math.

  char* ws = (char*)d_ws;
  double* r_p = (double*)ws;                       // 4096 f64 = 32 KB
  double* r_lp = (double*)(ws + 32768);            // 4096 f64 = 32 KB
  float* r_v = (float*)(ws + 65536);               // 4096 f32 = 16 KB
  int* r_i = (int*)(ws + 81920);                   // 4096 i32 = 16 KB
  float* out = (float*)d_out;

  hipLaunchKernelGGL(rowstats, dim3(NROWS), dim3(256), 0, stream,
                     logits, r_v, r_i, r_p, r_lp);
  hipLaunchKernelGGL(beam_sim, dim3(B_), dim3(64), 0, stream,
                     r_v, r_i, r_p, r_lp, out);
}

// Round 3
// 112.995 us; speedup vs baseline: 2.2855x; 2.2855x over previous
//
#include <hip/hip_runtime.h>
#include <math.h>

#define T_ 128
#define B_ 8
#define C_ 25000
#define W_ 4
#define NROWS (T_ * B_)   // 1024

// Tie-exact comparator: value desc, index asc (matches lax.top_k tie rule).
__device__ __forceinline__ bool better(float av, int ai, float bv, int bi) {
  return (av > bv) || (av == bv && ai < bi);
}

// ---------------------------------------------------------------------------
// Kernel A: per row (t,b): top-4 (value,index) of raw logits (exact f32 bit
// comparisons), online-softmax denominator, and f64 p_k = exp(v_k - v_0)/den,
// lp_k = log(p_k). One block of 256 threads per row.
// Output layout is [b][t][k] so beam_sim's per-batch slice is contiguous.
// ---------------------------------------------------------------------------
__global__ __launch_bounds__(256) void rowstats(
    const float* __restrict__ logits,
    float* __restrict__ r_v, int* __restrict__ r_i,
    double* __restrict__ r_p, double* __restrict__ r_lp) {
  const int row = blockIdx.x;  // row = t*B + b (input layout)
  const float4* __restrict__ x4 =
      reinterpret_cast<const float4*>(logits + (size_t)row * C_);
  const int tid = threadIdx.x;

  float tv[4] = {-INFINITY, -INFINITY, -INFINITY, -INFINITY};
  int ti[4] = {0x7fffffff, 0x7fffffff, 0x7fffffff, 0x7fffffff};
  float m = -INFINITY, s = 0.0f;

  for (int i = tid; i < C_ / 4; i += 256) {
    float4 q = x4[i];
    float vals[4] = {q.x, q.y, q.z, q.w};
#pragma unroll
    for (int j = 0; j < 4; ++j) {
      float val = vals[j];
      int gi = 4 * i + j;
      if (val > m) {
        s = s * expf(m - val) + 1.0f;
        m = val;
      } else {
        s += expf(val - m);
      }
      // gate: only enter the insertion chain if it beats the current 4th
      if (better(val, gi, tv[3], ti[3])) {
        float cv = val; int ci2 = gi;
#pragma unroll
        for (int k = 0; k < 4; ++k) {
          if (better(cv, ci2, tv[k], ti[k])) {
            float t0 = tv[k]; int t1 = ti[k];
            tv[k] = cv; ti[k] = ci2;
            cv = t0; ci2 = t1;
          }
        }
      }
    }
  }

  __shared__ float sv[256][4];
  __shared__ int si[256][4];
  __shared__ float smm[256], sms[256];
#pragma unroll
  for (int k = 0; k < 4; ++k) { sv[tid][k] = tv[k]; si[tid][k] = ti[k]; }
  smm[tid] = m; sms[tid] = s;
  __syncthreads();

  for (int off = 128; off > 0; off >>= 1) {
    if (tid < off) {
      float m1 = smm[tid], s1 = sms[tid];
      float m2 = smm[tid + off], s2 = sms[tid + off];
      if (m2 > m1) { s1 = s1 * expf(m1 - m2) + s2; m1 = m2; }
      else { s1 = s1 + s2 * expf(m2 - m1); }
      smm[tid] = m1; sms[tid] = s1;
      float a0[4], ov[4]; int a1[4], oi[4];
#pragma unroll
      for (int k = 0; k < 4; ++k) { a0[k] = sv[tid][k]; a1[k] = si[tid][k]; }
      int pa = 0, pb = 0;
#pragma unroll
      for (int k = 0; k < 4; ++k) {
        float bv_ = sv[tid + off][pb]; int bi_ = si[tid + off][pb];
        if (better(a0[pa], a1[pa], bv_, bi_)) { ov[k] = a0[pa]; oi[k] = a1[pa]; ++pa; }
        else { ov[k] = bv_; oi[k] = bi_; ++pb; }
      }
#pragma unroll
      for (int k = 0; k < 4; ++k) { sv[tid][k] = ov[k]; si[tid][k] = oi[k]; }
    }
    __syncthreads();
  }

  if (tid == 0) {
    const int t = row / B_, b = row % B_;
    const int orow = b * T_ + t;  // transposed layout for beam_sim
    double den = (double)sms[0];
    double v0 = (double)sv[0][0];
#pragma unroll
    for (int k = 0; k < 4; ++k) {
      r_v[orow * 4 + k] = sv[0][k];
      r_i[orow * 4 + k] = si[0][k];
      double p = exp((double)sv[0][k] - v0) / den;
      r_p[orow * 4 + k] = p;
      r_lp[orow * 4 + k] = log(p);
    }
  }
}

// ---------------------------------------------------------------------------
// Kernel B: beam recursion per batch. All stats staged in LDS; serial work on
// thread 0 touches ONLY tie steps (v[0]==v[1] bitwise); non-tie steps are a
// closed form (every beam appends ci[0]; logs shift by a shared prefix-sum
// constant; parent = identity). Bit-faithful to the round-2 general path:
//  - fast step == general path outcome when v[0]!=v[1] (logs stay sorted
//    desc; stable sort of uniformly-shifted keys is identity; P=identity,
//    Ch=ci[0], scor=p[0]).
//  - batched f64 adds vs sequential: only bit-equal fork twins must stay
//    equal, and they see identical expressions; distinct-history log gaps
//    (>=~1e-7 from distinct f32 inputs) dwarf reassociation noise (~1e-13).
// ---------------------------------------------------------------------------
__global__ __launch_bounds__(128) void beam_sim(
    const float* __restrict__ r_v, const int* __restrict__ r_i,
    const double* __restrict__ r_p, const double* __restrict__ r_lp,
    float* __restrict__ out) {
  const int b = blockIdx.x;
  const int tid = threadIdx.x;

  __shared__ float lv[T_][4];
  __shared__ int lci[T_][4];
  __shared__ double lpk[T_][4];   // log p_k
  __shared__ double lpp[T_][4];   // p_k
  __shared__ double S[T_];        // S[t] = sum_{u=1..t} log p_0(u), S[0]=0
  __shared__ unsigned char isslow[T_];
  __shared__ int Pst[T_][4], Chst[T_][4];  // only written at tie steps
  __shared__ int seq[W_][T_];     // seq[w][t] = char emitted at step t
  __shared__ double sh_scores[W_], sh_logs[W_];

  const size_t base = (size_t)b * T_ * 4;
  for (int e = tid; e < T_ * 4; e += 128) {
    lv[e >> 2][e & 3] = r_v[base + e];
    lci[e >> 2][e & 3] = r_i[base + e];
    lpk[e >> 2][e & 3] = r_lp[base + e];
    lpp[e >> 2][e & 3] = r_p[base + e];
  }
  __syncthreads();
  for (int t = tid; t < T_; t += 128) {
    isslow[t] = (t >= 1) &&
        (__float_as_uint(lv[t][0]) == __float_as_uint(lv[t][1]));
  }
  __syncthreads();

  if (tid == 0) {
    // prefix sums of log p_0
    double acc = 0.0;
    S[0] = 0.0;
    for (int t = 1; t < T_; ++t) { acc += lpk[t][0]; S[t] = acc; }

    // t=0 seed (nw=1): candidates are (parent 0, k=0..3) in order; nl sorted
    // desc already (stable) -> identity order.
    double logs[4], scor[4];
    for (int j = 0; j < 4; ++j) logs[j] = lpk[0][j];

    int tprev = 0;
    int lastSlow = -1;
    for (int ts = 1; ts < T_; ++ts) {
      if (!isslow[ts]) continue;
      // advance logs through the fast steps (tprev, ts)
      double add = S[ts - 1] - S[tprev];
      for (int j = 0; j < 4; ++j) logs[j] += add;

      // general tie-exact step at ts (nw=4)
      float v[4]; int ci[4];
      for (int k = 0; k < 4; ++k) { v[k] = lv[ts][k]; ci[k] = lci[ts][k]; }
      int sw[4], sc[4], sk[4]; int ns = 0; int k = 0;
      while (ns < 4 && k < 4) {
        int k2 = k;
        while (k2 + 1 < 4 &&
               __float_as_uint(v[k2 + 1]) == __float_as_uint(v[k])) ++k2;
        for (int w = 0; w < 4 && ns < 4; ++w)
          for (int kk = k; kk <= k2 && ns < 4; ++kk) {
            sw[ns] = w; sc[ns] = ci[kk]; sk[ns] = kk; ++ns;
          }
        k = k2 + 1;
      }
      double nl[4];
      for (int j = 0; j < 4; ++j) nl[j] = logs[sw[j]] + lpk[ts][sk[j]];
      int ord[4] = {0, 1, 2, 3};
      for (int a = 1; a < 4; ++a) {
        int o = ord[a]; int bb = a;
        while (bb > 0 && nl[ord[bb - 1]] < nl[o]) { ord[bb] = ord[bb - 1]; --bb; }
        ord[bb] = o;
      }
      for (int j = 0; j < 4; ++j) {
        Pst[ts][j] = sw[ord[j]];
        Chst[ts][j] = sc[ord[j]];
      }
      double tl[4];
      for (int j = 0; j < 4; ++j) tl[j] = nl[ord[j]];
      for (int j = 0; j < 4; ++j) logs[j] = tl[j];
      if (ts == T_ - 1)
        for (int j = 0; j < 4; ++j) scor[j] = lpp[ts][sk[ord[j]]];
      tprev = ts;
      lastSlow = ts;
    }
    // tail: fast steps (tprev, T_-1]
    double add = S[T_ - 1] - S[tprev];
    for (int j = 0; j < 4; ++j) logs[j] += add;
    if (lastSlow != T_ - 1)
      for (int j = 0; j < 4; ++j) scor[j] = lpp[T_ - 1][0];

    // final stable sort by f32-cast scores, desc
    float sf[4];
    for (int j = 0; j < 4; ++j) sf[j] = (float)scor[j];
    int ford[4] = {0, 1, 2, 3};
    for (int a = 1; a < 4; ++a) {
      int o = ford[a]; int bb = a;
      while (bb > 0 && sf[ford[bb - 1]] < sf[o]) { ford[bb] = ford[bb - 1]; --bb; }
      ford[bb] = o;
    }

    // backtrack
    for (int w = 0; w < 4; ++w) {
      int j = ford[w];
      sh_scores[w] = scor[j];
      sh_logs[w] = logs[j];
      for (int t = T_ - 1; t >= 1; --t) {
        if (isslow[t]) { seq[w][t] = Chst[t][j]; j = Pst[t][j]; }
        else { seq[w][t] = lci[t][0]; }
      }
      seq[w][0] = lci[0][j];  // t=0: parent is beam 0 for all
    }
  }
  __syncthreads();

  // outputs: seqs [B][W][T+1], scores [B][W], logs [B][W]
  for (int e = tid; e < W_ * (T_ + 1); e += 128) {
    int w = e / (T_ + 1), p = e % (T_ + 1);
    int c = (p == 0) ? 0 : seq[w][p - 1];
    if (c == 1) c = 0;  // EOS -> BLANK
    out[(size_t)(b * W_ + w) * (T_ + 1) + p] = (float)c;
  }
  if (tid < W_) {
    out[B_ * W_ * (T_ + 1) + b * W_ + tid] = (float)sh_scores[tid];
    out[B_ * W_ * (T_ + 1) + B_ * W_ + b * W_ + tid] = (float)sh_logs[tid];
  }
}

// ---------------------------------------------------------------------------
extern "C" void kernel_launch(void* const* d_in, const int* in_sizes, int n_in,
                              void* d_out, int out_size, void* d_ws,
                              size_t ws_size, hipStream_t stream) {
  const float* logits = (const float*)d_in[0];
  // d_in[1] = seq_len (all == T): unused by the reference math.

  char* ws = (char*)d_ws;
  double* r_p = (double*)ws;                       // 4096 f64 = 32 KB
  double* r_lp = (double*)(ws + 32768);            // 4096 f64 = 32 KB
  float* r_v = (float*)(ws + 65536);               // 4096 f32 = 16 KB
  int* r_i = (int*)(ws + 81920);                   // 4096 i32 = 16 KB
  float* out = (float*)d_out;

  hipLaunchKernelGGL(rowstats, dim3(NROWS), dim3(256), 0, stream,
                     logits, r_v, r_i, r_p, r_lp);
  hipLaunchKernelGGL(beam_sim, dim3(B_), dim3(128), 0, stream,
                     r_v, r_i, r_p, r_lp, out);
}

// Round 4
// 46.940 us; speedup vs baseline: 5.5017x; 2.4072x over previous
//
#include <hip/hip_runtime.h>
#include <math.h>

#define T_ 128
#define B_ 8
#define C_ 25000
#define W_ 4
#define NROWS (T_ * B_)   // 1024
#define NT4 (C_ / 4)      // 6250 float4 per row

// Tie-exact comparator: value desc, index asc (matches lax.top_k tie rule).
__device__ __forceinline__ bool better(float av, int ai, float bv, int bi) {
  return (av > bv) || (av == bv && ai < bi);
}

// ---------------------------------------------------------------------------
// Kernel A: per row (t,b): top-4 (value,index) of raw logits (exact f32 bit
// comparisons) and denom' = sum(exp(x)) (NO max subtraction: per-row constant
// rescale of the softmax denominator shifts all log p_k equally, so no
// comparison can flip; |x|<~6 so exp(x) is overflow-safe in f32).
// f64 p_k = exp(v_k)/denom', lp_k = log(p_k). 512 threads/block, 1 block/row.
// ---------------------------------------------------------------------------
__global__ __launch_bounds__(512) void rowstats(
    const float* __restrict__ logits,
    float* __restrict__ r_v, int* __restrict__ r_i,
    double* __restrict__ r_p, double* __restrict__ r_lp) {
  const int row = blockIdx.x;  // row = t*B + b (input layout)
  const float4* __restrict__ x4 =
      reinterpret_cast<const float4*>(logits + (size_t)row * C_);
  const int tid = threadIdx.x;

  float tv[4] = {-INFINITY, -INFINITY, -INFINITY, -INFINITY};
  int ti[4] = {0x7fffffff, 0x7fffffff, 0x7fffffff, 0x7fffffff};
  float s0 = 0.0f, s1 = 0.0f;

  auto ins = [&](float cv, int ci2) {
#pragma unroll
    for (int k = 0; k < 4; ++k) {
      if (better(cv, ci2, tv[k], ti[k])) {
        float t0 = tv[k]; int t1 = ti[k];
        tv[k] = cv; ti[k] = ci2;
        cv = t0; ci2 = t1;
      }
    }
  };

#pragma unroll 4
  for (int i = tid; i < NT4; i += 512) {
    float4 q = x4[i];
    s0 += __expf(q.x) + __expf(q.y);
    s1 += __expf(q.z) + __expf(q.w);
    const int gi = 4 * i;
    if (better(q.x, gi + 0, tv[3], ti[3])) ins(q.x, gi + 0);
    if (better(q.y, gi + 1, tv[3], ti[3])) ins(q.y, gi + 1);
    if (better(q.z, gi + 2, tv[3], ti[3])) ins(q.z, gi + 2);
    if (better(q.w, gi + 3, tv[3], ti[3])) ins(q.w, gi + 3);
  }

  __shared__ float sv[512][4];
  __shared__ int si[512][4];
  __shared__ double ss[512];
#pragma unroll
  for (int k = 0; k < 4; ++k) { sv[tid][k] = tv[k]; si[tid][k] = ti[k]; }
  ss[tid] = (double)s0 + (double)s1;
  __syncthreads();

  for (int off = 256; off > 0; off >>= 1) {
    if (tid < off) {
      ss[tid] += ss[tid + off];
      // merge two sorted-4 lists (2-pointer; at pick k, pa+pb==k<=3, safe)
      float a0[4], ov[4]; int a1[4], oi[4];
#pragma unroll
      for (int k = 0; k < 4; ++k) { a0[k] = sv[tid][k]; a1[k] = si[tid][k]; }
      int pa = 0, pb = 0;
#pragma unroll
      for (int k = 0; k < 4; ++k) {
        float bv_ = sv[tid + off][pb]; int bi_ = si[tid + off][pb];
        if (better(a0[pa], a1[pa], bv_, bi_)) { ov[k] = a0[pa]; oi[k] = a1[pa]; ++pa; }
        else { ov[k] = bv_; oi[k] = bi_; ++pb; }
      }
#pragma unroll
      for (int k = 0; k < 4; ++k) { sv[tid][k] = ov[k]; si[tid][k] = oi[k]; }
    }
    __syncthreads();
  }

  if (tid == 0) {
    const int t = row / B_, b = row % B_;
    const int orow = b * T_ + t;  // transposed layout for beam_sim
    double den = ss[0];
#pragma unroll
    for (int k = 0; k < 4; ++k) {
      r_v[orow * 4 + k] = sv[0][k];
      r_i[orow * 4 + k] = si[0][k];
      double p = exp((double)sv[0][k]) / den;
      r_p[orow * 4 + k] = p;
      r_lp[orow * 4 + k] = log(p);
    }
  }
}

// ---------------------------------------------------------------------------
// Kernel B: beam recursion per batch, one wave (64 threads) per block.
//  - tie steps (v[0]==v[1] bitwise) found via __ballot -> two u64 masks
//  - S[t] = prefix sum of log p_0 via 6-step __shfl_up wave scan (f64)
//  - thread 0 serial work is O(#tie steps): between ties, every beam appends
//    ci[0], logs shift by the shared constant S[ts-1]-S[tprev], parent=id,
//    stable re-sort = identity (proof: logs stay sorted desc; uniform shift).
//  - backtrack: fast steps filled in parallel (char independent of beam);
//    lanes 0..3 walk only tie steps (descending bit iteration).
// Bit-faithfulness: only bit-equal fork twins must remain equal and they see
// identical f64 expressions; distinct-history log gaps (>=~1e-7) dwarf scan
// reassociation noise (~1e-13).
// ---------------------------------------------------------------------------
__global__ __launch_bounds__(64) void beam_sim(
    const float* __restrict__ r_v, const int* __restrict__ r_i,
    const double* __restrict__ r_p, const double* __restrict__ r_lp,
    float* __restrict__ out) {
  const int b = blockIdx.x;
  const int tid = threadIdx.x;  // 0..63

  __shared__ float lv[T_][4];
  __shared__ int lci[T_][4];
  __shared__ double lpk[T_][4];   // log p_k
  __shared__ double lpp[T_][4];   // p_k
  __shared__ double S[T_];        // S[t] = sum_{u=1..t} log p_0(u)
  __shared__ int Pst[T_][4], Chst[T_][4];  // only written at tie steps
  __shared__ int seq[W_][T_];     // seq[w][t] = char emitted at step t
  __shared__ double sh_scores[W_], sh_logs[W_];
  __shared__ int sh_ford[W_];

  const size_t base = (size_t)b * T_ * 4;
  for (int e = tid; e < T_ * 4; e += 64) {
    lv[e >> 2][e & 3] = r_v[base + e];
    lci[e >> 2][e & 3] = r_i[base + e];
    lpk[e >> 2][e & 3] = r_lp[base + e];
    lpp[e >> 2][e & 3] = r_p[base + e];
  }
  __syncthreads();

  // tie masks: bit t of mask0 = slow(t), t in [0,64); mask1 -> t in [64,128)
  bool slA = (tid >= 1) &&
      (__float_as_uint(lv[tid][0]) == __float_as_uint(lv[tid][1]));
  bool slB =
      (__float_as_uint(lv[tid + 64][0]) == __float_as_uint(lv[tid + 64][1]));
  const unsigned long long mask0 = __ballot(slA);
  const unsigned long long mask1 = __ballot(slB);

  // wave-parallel inclusive prefix sum of e_t = lpk[t][0] (e_0 := 0)
  {
    const int t0 = 2 * tid, t1 = 2 * tid + 1;
    double e0 = (t0 >= 1) ? lpk[t0][0] : 0.0;
    double e1 = lpk[t1][0];
    double pair = e0 + e1;
    double sc = pair;
#pragma unroll
    for (int d = 1; d < 64; d <<= 1) {
      double o = __shfl_up(sc, d, 64);
      if (tid >= d) sc += o;
    }
    double excl = sc - pair;
    S[t0] = excl + e0;
    S[t1] = sc;
  }

  // parallel fill of fast-step chars (beam-independent: always lci[t][0])
  for (int t = tid + 1; t < T_; t += 64) {  // stride 64, covers 1..127 in 2 iters
    bool slow = (t < 64) ? ((mask0 >> t) & 1ull) : ((mask1 >> (t - 64)) & 1ull);
    if (!slow) {
      int c = lci[t][0];
      seq[0][t] = c; seq[1][t] = c; seq[2][t] = c; seq[3][t] = c;
    }
  }
  __syncthreads();

  if (tid == 0) {
    double logs[4], scor[4] = {0.0, 0.0, 0.0, 0.0};
    for (int j = 0; j < 4; ++j) logs[j] = lpk[0][j];  // t=0 seed (nw=1)
    int tprev = 0, lastSlow = -1;

    unsigned long long mm = mask0;
    int phase = 0;
    while (true) {
      if (mm == 0) {
        if (phase == 0) { mm = mask1; phase = 1; continue; }
        break;
      }
      int bpos = __builtin_ctzll(mm); mm &= mm - 1;
      int ts = bpos + (phase ? 64 : 0);

      // advance logs through fast steps (tprev, ts)
      double add = S[ts - 1] - S[tprev];
      for (int j = 0; j < 4; ++j) logs[j] += add;

      // general tie-exact step at ts (nw=4): candidate order =
      // (value-bits desc, beam asc, char asc) == flattened top_k tie rule
      float v[4]; int ci[4];
      for (int k = 0; k < 4; ++k) { v[k] = lv[ts][k]; ci[k] = lci[ts][k]; }
      int sw[4], sc_[4], sk[4]; int ns = 0; int k = 0;
      while (ns < 4 && k < 4) {
        int k2 = k;
        while (k2 + 1 < 4 &&
               __float_as_uint(v[k2 + 1]) == __float_as_uint(v[k])) ++k2;
        for (int w = 0; w < 4 && ns < 4; ++w)
          for (int kk = k; kk <= k2 && ns < 4; ++kk) {
            sw[ns] = w; sc_[ns] = ci[kk]; sk[ns] = kk; ++ns;
          }
        k = k2 + 1;
      }
      double nl[4];
      for (int j = 0; j < 4; ++j) nl[j] = logs[sw[j]] + lpk[ts][sk[j]];
      int ord[4] = {0, 1, 2, 3};
      for (int a = 1; a < 4; ++a) {
        int o = ord[a]; int bb = a;
        while (bb > 0 && nl[ord[bb - 1]] < nl[o]) { ord[bb] = ord[bb - 1]; --bb; }
        ord[bb] = o;
      }
      for (int j = 0; j < 4; ++j) {
        Pst[ts][j] = sw[ord[j]];
        Chst[ts][j] = sc_[ord[j]];
      }
      double tl[4];
      for (int j = 0; j < 4; ++j) tl[j] = nl[ord[j]];
      for (int j = 0; j < 4; ++j) logs[j] = tl[j];
      if (ts == T_ - 1)
        for (int j = 0; j < 4; ++j) scor[j] = lpp[ts][sk[ord[j]]];
      tprev = ts;
      lastSlow = ts;
    }
    // tail: fast steps (tprev, T_-1]
    double add = S[T_ - 1] - S[tprev];
    for (int j = 0; j < 4; ++j) logs[j] += add;
    if (lastSlow != T_ - 1)
      for (int j = 0; j < 4; ++j) scor[j] = lpp[T_ - 1][0];

    // final stable sort by f32-cast scores, desc (matches argsort(-scores))
    float sf[4];
    for (int j = 0; j < 4; ++j) sf[j] = (float)scor[j];
    int ford[4] = {0, 1, 2, 3};
    for (int a = 1; a < 4; ++a) {
      int o = ford[a]; int bb = a;
      while (bb > 0 && sf[ford[bb - 1]] < sf[o]) { ford[bb] = ford[bb - 1]; --bb; }
      ford[bb] = o;
    }
    for (int w = 0; w < 4; ++w) {
      sh_ford[w] = ford[w];
      sh_scores[w] = scor[ford[w]];
      sh_logs[w] = logs[ford[w]];
    }
  }
  __syncthreads();

  // lanes 0..3: walk tie steps (descending) to resolve beam-dependent chars
  if (tid < W_) {
    int j = sh_ford[tid];
    unsigned long long mm = mask1;
    int phase = 1;
    while (true) {
      if (mm == 0) {
        if (phase == 1) { mm = mask0; phase = 0; continue; }
        break;
      }
      int bpos = 63 - __builtin_clzll(mm); mm &= ~(1ull << bpos);
      int ts = bpos + (phase ? 64 : 0);
      seq[tid][ts] = Chst[ts][j];
      j = Pst[ts][j];
    }
    seq[tid][0] = lci[0][j];  // t=0: char chosen by the surviving seed index
  }
  __syncthreads();

  // outputs: seqs [B][W][T+1], scores [B][W], logs [B][W]
  for (int e = tid; e < W_ * (T_ + 1); e += 64) {
    int w = e / (T_ + 1), p = e % (T_ + 1);
    int c = (p == 0) ? 0 : seq[w][p - 1];
    if (c == 1) c = 0;  // EOS -> BLANK
    out[(size_t)(b * W_ + w) * (T_ + 1) + p] = (float)c;
  }
  if (tid < W_) {
    out[B_ * W_ * (T_ + 1) + b * W_ + tid] = (float)sh_scores[tid];
    out[B_ * W_ * (T_ + 1) + B_ * W_ + b * W_ + tid] = (float)sh_logs[tid];
  }
}

// ---------------------------------------------------------------------------
extern "C" void kernel_launch(void* const* d_in, const int* in_sizes, int n_in,
                              void* d_out, int out_size, void* d_ws,
                              size_t ws_size, hipStream_t stream) {
  const float* logits = (const float*)d_in[0];
  // d_in[1] = seq_len (all == T): unused by the reference math.

  char* ws = (char*)d_ws;
  double* r_p = (double*)ws;                       // 4096 f64 = 32 KB
  double* r_lp = (double*)(ws + 32768);            // 4096 f64 = 32 KB
  float* r_v = (float*)(ws + 65536);               // 4096 f32 = 16 KB
  int* r_i = (int*)(ws + 81920);                   // 4096 i32 = 16 KB
  float* out = (float*)d_out;

  hipLaunchKernelGGL(rowstats, dim3(NROWS), dim3(512), 0, stream,
                     logits, r_v, r_i, r_p, r_lp);
  hipLaunchKernelGGL(beam_sim, dim3(B_), dim3(64), 0, stream,
                     r_v, r_i, r_p, r_lp, out);
}

// Round 5
// 41.722 us; speedup vs baseline: 6.1897x; 1.1251x over previous
//
#include <hip/hip_runtime.h>
#include <math.h>

#define T_ 128
#define B_ 8
#define C_ 25000
#define W_ 4
#define NROWS (T_ * B_)   // 1024
#define NT4 (C_ / 4)      // 6250 float4 per row

// Tie-exact comparator: value desc, index asc (matches lax.top_k tie rule).
__device__ __forceinline__ bool better(float av, int ai, float bv, int bi) {
  return (av > bv) || (av == bv && ai < bi);
}

// ---------------------------------------------------------------------------
// Kernel A (fused): per row (t,b):
//   phase 1 (all rows, branchless): argmax (value,index, first-occurrence),
//     second-max VALUE (for exact duplicate-max detection), den=sum(__expf(x)).
//     Writes lp0 = v0 - log(den), p0 = exp(lp0), ci0, tied flag.
//   phase 2 (only t==0 rows or tied rows, ~24 blocks): exact top-4
//     (value,index) re-scan with the gated insertion path; writes 4-wide
//     arrays t4v/t4i/t4lp/t4p using the SAME den (t4lp[0] bit-equals lp0).
// ---------------------------------------------------------------------------
__global__ __launch_bounds__(512) void rowstats(
    const float* __restrict__ logits,
    double* __restrict__ d_lp0, double* __restrict__ d_p0,
    int* __restrict__ d_ci0, int* __restrict__ d_tied,
    float* __restrict__ d_t4v, int* __restrict__ d_t4i,
    double* __restrict__ d_t4lp, double* __restrict__ d_t4p) {
  const int row = blockIdx.x;  // row = t*B + b (input layout)
  const float4* __restrict__ x4 =
      reinterpret_cast<const float4*>(logits + (size_t)row * C_);
  const int tid = threadIdx.x;

  // ---- phase 1: branchless per-thread (m1,idx), m2 value, exp-sum ----
  float m1 = -INFINITY, m2 = -INFINITY;
  int idx = 0;
  float s0 = 0.0f, s1 = 0.0f;

#pragma unroll 4
  for (int i = tid; i < NT4; i += 512) {
    float4 q = x4[i];
    const int gi = 4 * i;
    s0 += __expf(q.x) + __expf(q.y);
    s1 += __expf(q.z) + __expf(q.w);
    // elem x
    { bool c = q.x > m1; m2 = fmaxf(m2, fminf(q.x, m1));
      idx = c ? (gi + 0) : idx; m1 = fmaxf(m1, q.x); }
    { bool c = q.y > m1; m2 = fmaxf(m2, fminf(q.y, m1));
      idx = c ? (gi + 1) : idx; m1 = fmaxf(m1, q.y); }
    { bool c = q.z > m1; m2 = fmaxf(m2, fminf(q.z, m1));
      idx = c ? (gi + 2) : idx; m1 = fmaxf(m1, q.z); }
    { bool c = q.w > m1; m2 = fmaxf(m2, fminf(q.w, m1));
      idx = c ? (gi + 3) : idx; m1 = fmaxf(m1, q.w); }
  }

  // wave butterfly reduce (no LDS, no syncs)
  double sumd = (double)s0 + (double)s1;
#pragma unroll
  for (int d = 1; d < 64; d <<= 1) {
    float om1 = __shfl_xor(m1, d, 64);
    float om2 = __shfl_xor(m2, d, 64);
    int oidx = __shfl_xor(idx, d, 64);
    double osum = __shfl_xor(sumd, d, 64);
    sumd += osum;
    float nm2 = fmaxf(fminf(m1, om1), fmaxf(m2, om2));
    bool take = (om1 > m1) || (om1 == m1 && oidx < idx);
    m1 = take ? om1 : m1;
    idx = take ? oidx : idx;
    m2 = nm2;
  }

  __shared__ float g_m1[8], g_m2[8];
  __shared__ int g_idx[8];
  __shared__ double g_sum[8];
  __shared__ double sh_logden;
  __shared__ int sh_phase2;
  if ((tid & 63) == 0) {
    int w = tid >> 6;
    g_m1[w] = m1; g_m2[w] = m2; g_idx[w] = idx; g_sum[w] = sumd;
  }
  __syncthreads();

  if (tid == 0) {
    float M1 = g_m1[0], M2 = g_m2[0];
    int I = g_idx[0];
    double S = g_sum[0];
#pragma unroll
    for (int w = 1; w < 8; ++w) {
      S += g_sum[w];
      float b1 = g_m1[w], b2 = g_m2[w];
      float nm2 = fmaxf(fminf(M1, b1), fmaxf(M2, b2));
      bool take = (b1 > M1) || (b1 == M1 && g_idx[w] < I);
      if (take) { M1 = b1; I = g_idx[w]; }
      M2 = nm2;
    }
    const int t = row / B_, b = row % B_;
    const int orow = b * T_ + t;  // transposed layout for beam_sim
    double logden = log(S);
    double lp0 = (double)M1 - logden;
    d_lp0[orow] = lp0;
    d_p0[orow] = exp(lp0);
    d_ci0[orow] = I;
    int tied = (__float_as_uint(M1) == __float_as_uint(M2)) ? 1 : 0;
    d_tied[orow] = tied;
    sh_logden = logden;
    sh_phase2 = tied | (t == 0 ? 1 : 0);
  }
  __syncthreads();

  if (!sh_phase2) return;

  // ---- phase 2 (rare): exact top-4 (value,index), row re-scan (L2-warm) ----
  float tv[4] = {-INFINITY, -INFINITY, -INFINITY, -INFINITY};
  int ti4[4] = {0x7fffffff, 0x7fffffff, 0x7fffffff, 0x7fffffff};
  auto ins = [&](float cv, int ci2) {
#pragma unroll
    for (int k = 0; k < 4; ++k) {
      if (better(cv, ci2, tv[k], ti4[k])) {
        float t0 = tv[k]; int t1 = ti4[k];
        tv[k] = cv; ti4[k] = ci2;
        cv = t0; ci2 = t1;
      }
    }
  };
  for (int i = tid; i < NT4; i += 512) {
    float4 q = x4[i];
    const int gi = 4 * i;
    if (better(q.x, gi + 0, tv[3], ti4[3])) ins(q.x, gi + 0);
    if (better(q.y, gi + 1, tv[3], ti4[3])) ins(q.y, gi + 1);
    if (better(q.z, gi + 2, tv[3], ti4[3])) ins(q.z, gi + 2);
    if (better(q.w, gi + 3, tv[3], ti4[3])) ins(q.w, gi + 3);
  }

  __shared__ float sv[512][4];
  __shared__ int si[512][4];
#pragma unroll
  for (int k = 0; k < 4; ++k) { sv[tid][k] = tv[k]; si[tid][k] = ti4[k]; }
  __syncthreads();

  for (int off = 256; off > 0; off >>= 1) {
    if (tid < off) {
      float a0[4], ov[4]; int a1[4], oi[4];
#pragma unroll
      for (int k = 0; k < 4; ++k) { a0[k] = sv[tid][k]; a1[k] = si[tid][k]; }
      int pa = 0, pb = 0;
#pragma unroll
      for (int k = 0; k < 4; ++k) {
        float bv_ = sv[tid + off][pb]; int bi_ = si[tid + off][pb];
        if (better(a0[pa], a1[pa], bv_, bi_)) { ov[k] = a0[pa]; oi[k] = a1[pa]; ++pa; }
        else { ov[k] = bv_; oi[k] = bi_; ++pb; }
      }
#pragma unroll
      for (int k = 0; k < 4; ++k) { sv[tid][k] = ov[k]; si[tid][k] = oi[k]; }
    }
    __syncthreads();
  }

  if (tid == 0) {
    const int t = row / B_, b = row % B_;
    const int orow = b * T_ + t;
    double logden = sh_logden;
#pragma unroll
    for (int k = 0; k < 4; ++k) {
      d_t4v[orow * 4 + k] = sv[0][k];
      d_t4i[orow * 4 + k] = si[0][k];
      double lp = (double)sv[0][k] - logden;
      d_t4lp[orow * 4 + k] = lp;
      d_t4p[orow * 4 + k] = exp(lp);
    }
  }
}

// ---------------------------------------------------------------------------
// Kernel B: beam recursion per batch, one wave per block. Same semantics as
// round 4 (passed, absmax 0): tie steps from the tied flag; S[t] prefix-sum
// of lp0 via wave scan; thread 0 serial work O(#tie steps), reading 4-wide
// stats directly from global (only t=0 and tie rows are ever touched there);
// backtrack fast steps in parallel, tie steps by lanes 0..3.
// ---------------------------------------------------------------------------
__global__ __launch_bounds__(64) void beam_sim(
    const double* __restrict__ d_lp0, const double* __restrict__ d_p0,
    const int* __restrict__ d_ci0, const int* __restrict__ d_tied,
    const float* __restrict__ d_t4v, const int* __restrict__ d_t4i,
    const double* __restrict__ d_t4lp, const double* __restrict__ d_t4p,
    float* __restrict__ out) {
  const int b = blockIdx.x;
  const int tid = threadIdx.x;  // 0..63

  __shared__ double lp0[T_], p0v[T_];
  __shared__ int ci0[T_], tiedL[T_];
  __shared__ double S[T_];
  __shared__ int Pst[T_][4], Chst[T_][4];  // only written at tie steps
  __shared__ int seq[W_][T_];
  __shared__ double sh_scores[W_], sh_logs[W_];
  __shared__ int sh_ford[W_];

  const int base = b * T_;
  for (int e = tid; e < T_; e += 64) {
    lp0[e] = d_lp0[base + e];
    p0v[e] = d_p0[base + e];
    ci0[e] = d_ci0[base + e];
    tiedL[e] = d_tied[base + e];
  }
  __syncthreads();

  // tie masks (t=0 excluded: seed logic always uses full top-4 there)
  bool slA = (tid >= 1) && (tiedL[tid] != 0);
  bool slB = (tiedL[tid + 64] != 0);
  const unsigned long long mask0 = __ballot(slA);
  const unsigned long long mask1 = __ballot(slB);

  // wave-parallel inclusive prefix sum of e_t = lp0[t] (e_0 := 0)
  {
    const int t0 = 2 * tid, t1 = 2 * tid + 1;
    double e0 = (t0 >= 1) ? lp0[t0] : 0.0;
    double e1 = lp0[t1];
    double pair = e0 + e1;
    double sc = pair;
#pragma unroll
    for (int d = 1; d < 64; d <<= 1) {
      double o = __shfl_up(sc, d, 64);
      if (tid >= d) sc += o;
    }
    double excl = sc - pair;
    S[t0] = excl + e0;
    S[t1] = sc;
  }

  // parallel fill of fast-step chars (beam-independent: always ci0[t])
  for (int t = tid + 1; t < T_; t += 64) {
    bool slow = (t < 64) ? ((mask0 >> t) & 1ull) : ((mask1 >> (t - 64)) & 1ull);
    if (!slow) {
      int c = ci0[t];
      seq[0][t] = c; seq[1][t] = c; seq[2][t] = c; seq[3][t] = c;
    }
  }
  __syncthreads();

  if (tid == 0) {
    double logs[4], scor[4] = {0.0, 0.0, 0.0, 0.0};
    const int base4 = base * 4;
    for (int j = 0; j < 4; ++j) logs[j] = d_t4lp[base4 + j];  // t=0 seed
    int tprev = 0, lastSlow = -1;

    unsigned long long mm = mask0;
    int phase = 0;
    while (true) {
      if (mm == 0) {
        if (phase == 0) { mm = mask1; phase = 1; continue; }
        break;
      }
      int bpos = __builtin_ctzll(mm); mm &= mm - 1;
      int ts = bpos + (phase ? 64 : 0);

      double add = S[ts - 1] - S[tprev];
      for (int j = 0; j < 4; ++j) logs[j] += add;

      // general tie-exact step at ts: candidate order =
      // (value-bits desc, beam asc, char asc) == flattened top_k tie rule
      const int row4 = (base + ts) * 4;
      float v[4]; int ci[4]; double lpk4[4], pk4[4];
      for (int k = 0; k < 4; ++k) {
        v[k] = d_t4v[row4 + k];
        ci[k] = d_t4i[row4 + k];
        lpk4[k] = d_t4lp[row4 + k];
        pk4[k] = d_t4p[row4 + k];
      }
      int sw[4], sc_[4], sk[4]; int ns = 0; int k = 0;
      while (ns < 4 && k < 4) {
        int k2 = k;
        while (k2 + 1 < 4 &&
               __float_as_uint(v[k2 + 1]) == __float_as_uint(v[k])) ++k2;
        for (int w = 0; w < 4 && ns < 4; ++w)
          for (int kk = k; kk <= k2 && ns < 4; ++kk) {
            sw[ns] = w; sc_[ns] = ci[kk]; sk[ns] = kk; ++ns;
          }
        k = k2 + 1;
      }
      double nl[4];
      for (int j = 0; j < 4; ++j) nl[j] = logs[sw[j]] + lpk4[sk[j]];
      int ord[4] = {0, 1, 2, 3};
      for (int a = 1; a < 4; ++a) {
        int o = ord[a]; int bb = a;
        while (bb > 0 && nl[ord[bb - 1]] < nl[o]) { ord[bb] = ord[bb - 1]; --bb; }
        ord[bb] = o;
      }
      for (int j = 0; j < 4; ++j) {
        Pst[ts][j] = sw[ord[j]];
        Chst[ts][j] = sc_[ord[j]];
      }
      double tl[4];
      for (int j = 0; j < 4; ++j) tl[j] = nl[ord[j]];
      for (int j = 0; j < 4; ++j) logs[j] = tl[j];
      if (ts == T_ - 1)
        for (int j = 0; j < 4; ++j) scor[j] = pk4[sk[ord[j]]];
      tprev = ts;
      lastSlow = ts;
    }
    double add = S[T_ - 1] - S[tprev];
    for (int j = 0; j < 4; ++j) logs[j] += add;
    if (lastSlow != T_ - 1)
      for (int j = 0; j < 4; ++j) scor[j] = p0v[T_ - 1];

    // final stable sort by f32-cast scores, desc (matches argsort(-scores))
    float sf[4];
    for (int j = 0; j < 4; ++j) sf[j] = (float)scor[j];
    int ford[4] = {0, 1, 2, 3};
    for (int a = 1; a < 4; ++a) {
      int o = ford[a]; int bb = a;
      while (bb > 0 && sf[ford[bb - 1]] < sf[o]) { ford[bb] = ford[bb - 1]; --bb; }
      ford[bb] = o;
    }
    for (int w = 0; w < 4; ++w) {
      sh_ford[w] = ford[w];
      sh_scores[w] = scor[ford[w]];
      sh_logs[w] = logs[ford[w]];
    }
  }
  __syncthreads();

  // lanes 0..3: walk tie steps (descending) to resolve beam-dependent chars
  if (tid < W_) {
    int j = sh_ford[tid];
    unsigned long long mm = mask1;
    int phase = 1;
    while (true) {
      if (mm == 0) {
        if (phase == 1) { mm = mask0; phase = 0; continue; }
        break;
      }
      int bpos = 63 - __builtin_clzll(mm); mm &= ~(1ull << bpos);
      int ts = bpos + (phase ? 64 : 0);
      seq[tid][ts] = Chst[ts][j];
      j = Pst[ts][j];
    }
    seq[tid][0] = d_t4i[base * 4 + j];  // t=0 char of surviving seed index
  }
  __syncthreads();

  // outputs: seqs [B][W][T+1], scores [B][W], logs [B][W]
  for (int e = tid; e < W_ * (T_ + 1); e += 64) {
    int w = e / (T_ + 1), p = e % (T_ + 1);
    int c = (p == 0) ? 0 : seq[w][p - 1];
    if (c == 1) c = 0;  // EOS -> BLANK
    out[(size_t)(b * W_ + w) * (T_ + 1) + p] = (float)c;
  }
  if (tid < W_) {
    out[B_ * W_ * (T_ + 1) + b * W_ + tid] = (float)sh_scores[tid];
    out[B_ * W_ * (T_ + 1) + B_ * W_ + b * W_ + tid] = (float)sh_logs[tid];
  }
}

// ---------------------------------------------------------------------------
extern "C" void kernel_launch(void* const* d_in, const int* in_sizes, int n_in,
                              void* d_out, int out_size, void* d_ws,
                              size_t ws_size, hipStream_t stream) {
  const float* logits = (const float*)d_in[0];
  // d_in[1] = seq_len (all == T): unused by the reference math.

  char* ws = (char*)d_ws;
  double* d_lp0 = (double*)(ws + 0);        // 1024 f64 =  8 KB
  double* d_p0 = (double*)(ws + 8192);      // 1024 f64 =  8 KB
  double* d_t4lp = (double*)(ws + 16384);   // 4096 f64 = 32 KB
  double* d_t4p = (double*)(ws + 49152);    // 4096 f64 = 32 KB
  int* d_ci0 = (int*)(ws + 81920);          // 1024 i32 =  4 KB
  int* d_tied = (int*)(ws + 86016);         // 1024 i32 =  4 KB
  float* d_t4v = (float*)(ws + 90112);      // 4096 f32 = 16 KB
  int* d_t4i = (int*)(ws + 106496);         // 4096 i32 = 16 KB
  float* out = (float*)d_out;

  hipLaunchKernelGGL(rowstats, dim3(NROWS), dim3(512), 0, stream,
                     logits, d_lp0, d_p0, d_ci0, d_tied,
                     d_t4v, d_t4i, d_t4lp, d_t4p);
  hipLaunchKernelGGL(beam_sim, dim3(B_), dim3(64), 0, stream,
                     d_lp0, d_p0, d_ci0, d_tied,
                     d_t4v, d_t4i, d_t4lp, d_t4p, out);
}

// Round 6
// 41.219 us; speedup vs baseline: 6.2652x; 1.0122x over previous
//
#include <hip/hip_runtime.h>
#include <math.h>

#define T_ 128
#define B_ 8
#define C_ 25000
#define W_ 4
#define NROWS (T_ * B_)   // 1024
#define NT4 (C_ / 4)      // 6250 float4 per row; 6250 = 512*12 + 106

// Tie-exact comparator: value desc, index asc (matches lax.top_k tie rule).
__device__ __forceinline__ bool better(float av, int ai, float bv, int bi) {
  return (av > bv) || (av == bv && ai < bi);
}

// ---------------------------------------------------------------------------
// Kernel A (fused): per row (t,b):
//   phase 1 (all rows): argmax (value,index, first occurrence), second-max
//     VALUE (duplicate-max detection), den = sum(__expf(x)) — no max
//     subtraction (per-row constant rescale; |x|<~6 so f32-safe).
//     Loads are staged in register batches of 6 float4 BEFORE consumption to
//     maximize memory-level parallelism (latency-bound fix).
//   phase 2 (only t==0 or tied rows, ~10-30 blocks): exact top-4 re-scan
//     (L2-warm) with gated insertion; same den (t4lp[0] bit-equals lp0).
// ---------------------------------------------------------------------------
__global__ __launch_bounds__(512) void rowstats(
    const float* __restrict__ logits,
    double* __restrict__ d_lp0, double* __restrict__ d_p0,
    int* __restrict__ d_ci0, int* __restrict__ d_tied,
    float* __restrict__ d_t4v, int* __restrict__ d_t4i,
    double* __restrict__ d_t4lp, double* __restrict__ d_t4p) {
  const int row = blockIdx.x;  // row = t*B + b (input layout)
  const float4* __restrict__ x4 =
      reinterpret_cast<const float4*>(logits + (size_t)row * C_);
  const int tid = threadIdx.x;

  float m1 = -INFINITY, m2 = -INFINITY;
  int idx = 0;
  float s0 = 0.0f, s1 = 0.0f, s2 = 0.0f, s3 = 0.0f;

  auto consume = [&](float4 v, int gi) {
    s0 += __expf(v.x); s1 += __expf(v.y);
    s2 += __expf(v.z); s3 += __expf(v.w);
    {
      float old = m1; bool c = v.x > old;
      m2 = fmaxf(m2, fminf(v.x, old)); m1 = fmaxf(old, v.x);
      idx = c ? (gi + 0) : idx;
    }
    {
      float old = m1; bool c = v.y > old;
      m2 = fmaxf(m2, fminf(v.y, old)); m1 = fmaxf(old, v.y);
      idx = c ? (gi + 1) : idx;
    }
    {
      float old = m1; bool c = v.z > old;
      m2 = fmaxf(m2, fminf(v.z, old)); m1 = fmaxf(old, v.z);
      idx = c ? (gi + 2) : idx;
    }
    {
      float old = m1; bool c = v.w > old;
      m2 = fmaxf(m2, fminf(v.w, old)); m1 = fmaxf(old, v.w);
      idx = c ? (gi + 3) : idx;
    }
  };

  // ---- phase 1: two register-staged batches of 6 loads + guarded tail ----
  {
    float4 q[6];
#pragma unroll
    for (int k = 0; k < 6; ++k) q[k] = x4[tid + 512 * k];
#pragma unroll
    for (int k = 0; k < 6; ++k) consume(q[k], 4 * (tid + 512 * k));
#pragma unroll
    for (int k = 0; k < 6; ++k) q[k] = x4[tid + 512 * (6 + k)];
#pragma unroll
    for (int k = 0; k < 6; ++k) consume(q[k], 4 * (tid + 512 * (6 + k)));
    if (tid < NT4 - 512 * 12) {  // 106 tail quads
      float4 t = x4[tid + 512 * 12];
      consume(t, 4 * (tid + 512 * 12));
    }
  }

  // wave butterfly reduce (no LDS, no syncs)
  double sumd = (double)(s0 + s1) + (double)(s2 + s3);
#pragma unroll
  for (int d = 1; d < 64; d <<= 1) {
    float om1 = __shfl_xor(m1, d, 64);
    float om2 = __shfl_xor(m2, d, 64);
    int oidx = __shfl_xor(idx, d, 64);
    double osum = __shfl_xor(sumd, d, 64);
    sumd += osum;
    float nm2 = fmaxf(fminf(m1, om1), fmaxf(m2, om2));
    bool take = (om1 > m1) || (om1 == m1 && oidx < idx);
    m1 = take ? om1 : m1;
    idx = take ? oidx : idx;
    m2 = nm2;
  }

  __shared__ float g_m1[8], g_m2[8];
  __shared__ int g_idx[8];
  __shared__ double g_sum[8];
  __shared__ double sh_logden;
  __shared__ int sh_phase2;
  if ((tid & 63) == 0) {
    int w = tid >> 6;
    g_m1[w] = m1; g_m2[w] = m2; g_idx[w] = idx; g_sum[w] = sumd;
  }
  __syncthreads();

  if (tid == 0) {
    float M1 = g_m1[0], M2 = g_m2[0];
    int I = g_idx[0];
    double S = g_sum[0];
#pragma unroll
    for (int w = 1; w < 8; ++w) {
      S += g_sum[w];
      float b1 = g_m1[w], b2 = g_m2[w];
      float nm2 = fmaxf(fminf(M1, b1), fmaxf(M2, b2));
      bool take = (b1 > M1) || (b1 == M1 && g_idx[w] < I);
      if (take) { M1 = b1; I = g_idx[w]; }
      M2 = nm2;
    }
    const int t = row / B_, b = row % B_;
    const int orow = b * T_ + t;  // transposed layout for beam_sim
    double logden = log(S);
    double lp0 = (double)M1 - logden;
    d_lp0[orow] = lp0;
    d_p0[orow] = exp(lp0);
    d_ci0[orow] = I;
    int tied = (__float_as_uint(M1) == __float_as_uint(M2)) ? 1 : 0;
    d_tied[orow] = tied;
    sh_logden = logden;
    sh_phase2 = tied | (t == 0 ? 1 : 0);
  }
  __syncthreads();

  if (!sh_phase2) return;

  // ---- phase 2 (rare): exact top-4 (value,index), row re-scan (L2-warm) ----
  float tv[4] = {-INFINITY, -INFINITY, -INFINITY, -INFINITY};
  int ti4[4] = {0x7fffffff, 0x7fffffff, 0x7fffffff, 0x7fffffff};
  auto ins = [&](float cv, int ci2) {
#pragma unroll
    for (int k = 0; k < 4; ++k) {
      if (better(cv, ci2, tv[k], ti4[k])) {
        float t0 = tv[k]; int t1 = ti4[k];
        tv[k] = cv; ti4[k] = ci2;
        cv = t0; ci2 = t1;
      }
    }
  };
  for (int i = tid; i < NT4; i += 512) {
    float4 q = x4[i];
    const int gi = 4 * i;
    if (better(q.x, gi + 0, tv[3], ti4[3])) ins(q.x, gi + 0);
    if (better(q.y, gi + 1, tv[3], ti4[3])) ins(q.y, gi + 1);
    if (better(q.z, gi + 2, tv[3], ti4[3])) ins(q.z, gi + 2);
    if (better(q.w, gi + 3, tv[3], ti4[3])) ins(q.w, gi + 3);
  }

  __shared__ float sv[512][4];
  __shared__ int si[512][4];
#pragma unroll
  for (int k = 0; k < 4; ++k) { sv[tid][k] = tv[k]; si[tid][k] = ti4[k]; }
  __syncthreads();

  for (int off = 256; off > 0; off >>= 1) {
    if (tid < off) {
      float a0[4], ov[4]; int a1[4], oi[4];
#pragma unroll
      for (int k = 0; k < 4; ++k) { a0[k] = sv[tid][k]; a1[k] = si[tid][k]; }
      int pa = 0, pb = 0;
#pragma unroll
      for (int k = 0; k < 4; ++k) {
        float bv_ = sv[tid + off][pb]; int bi_ = si[tid + off][pb];
        if (better(a0[pa], a1[pa], bv_, bi_)) { ov[k] = a0[pa]; oi[k] = a1[pa]; ++pa; }
        else { ov[k] = bv_; oi[k] = bi_; ++pb; }
      }
#pragma unroll
      for (int k = 0; k < 4; ++k) { sv[tid][k] = ov[k]; si[tid][k] = oi[k]; }
    }
    __syncthreads();
  }

  if (tid == 0) {
    const int t = row / B_, b = row % B_;
    const int orow = b * T_ + t;
    double logden = sh_logden;
#pragma unroll
    for (int k = 0; k < 4; ++k) {
      d_t4v[orow * 4 + k] = sv[0][k];
      d_t4i[orow * 4 + k] = si[0][k];
      double lp = (double)sv[0][k] - logden;
      d_t4lp[orow * 4 + k] = lp;
      d_t4p[orow * 4 + k] = exp(lp);
    }
  }
}

// ---------------------------------------------------------------------------
// Kernel B: beam recursion per batch, one wave per block (unchanged from the
// passing round-5 version).
// ---------------------------------------------------------------------------
__global__ __launch_bounds__(64) void beam_sim(
    const double* __restrict__ d_lp0, const double* __restrict__ d_p0,
    const int* __restrict__ d_ci0, const int* __restrict__ d_tied,
    const float* __restrict__ d_t4v, const int* __restrict__ d_t4i,
    const double* __restrict__ d_t4lp, const double* __restrict__ d_t4p,
    float* __restrict__ out) {
  const int b = blockIdx.x;
  const int tid = threadIdx.x;  // 0..63

  __shared__ double lp0[T_], p0v[T_];
  __shared__ int ci0[T_], tiedL[T_];
  __shared__ double S[T_];
  __shared__ int Pst[T_][4], Chst[T_][4];  // only written at tie steps
  __shared__ int seq[W_][T_];
  __shared__ double sh_scores[W_], sh_logs[W_];
  __shared__ int sh_ford[W_];

  const int base = b * T_;
  for (int e = tid; e < T_; e += 64) {
    lp0[e] = d_lp0[base + e];
    p0v[e] = d_p0[base + e];
    ci0[e] = d_ci0[base + e];
    tiedL[e] = d_tied[base + e];
  }
  __syncthreads();

  // tie masks (t=0 excluded: seed logic always uses full top-4 there)
  bool slA = (tid >= 1) && (tiedL[tid] != 0);
  bool slB = (tiedL[tid + 64] != 0);
  const unsigned long long mask0 = __ballot(slA);
  const unsigned long long mask1 = __ballot(slB);

  // wave-parallel inclusive prefix sum of e_t = lp0[t] (e_0 := 0)
  {
    const int t0 = 2 * tid, t1 = 2 * tid + 1;
    double e0 = (t0 >= 1) ? lp0[t0] : 0.0;
    double e1 = lp0[t1];
    double pair = e0 + e1;
    double sc = pair;
#pragma unroll
    for (int d = 1; d < 64; d <<= 1) {
      double o = __shfl_up(sc, d, 64);
      if (tid >= d) sc += o;
    }
    double excl = sc - pair;
    S[t0] = excl + e0;
    S[t1] = sc;
  }

  // parallel fill of fast-step chars (beam-independent: always ci0[t])
  for (int t = tid + 1; t < T_; t += 64) {
    bool slow = (t < 64) ? ((mask0 >> t) & 1ull) : ((mask1 >> (t - 64)) & 1ull);
    if (!slow) {
      int c = ci0[t];
      seq[0][t] = c; seq[1][t] = c; seq[2][t] = c; seq[3][t] = c;
    }
  }
  __syncthreads();

  if (tid == 0) {
    double logs[4], scor[4] = {0.0, 0.0, 0.0, 0.0};
    const int base4 = base * 4;
    for (int j = 0; j < 4; ++j) logs[j] = d_t4lp[base4 + j];  // t=0 seed
    int tprev = 0, lastSlow = -1;

    unsigned long long mm = mask0;
    int phase = 0;
    while (true) {
      if (mm == 0) {
        if (phase == 0) { mm = mask1; phase = 1; continue; }
        break;
      }
      int bpos = __builtin_ctzll(mm); mm &= mm - 1;
      int ts = bpos + (phase ? 64 : 0);

      double add = S[ts - 1] - S[tprev];
      for (int j = 0; j < 4; ++j) logs[j] += add;

      // general tie-exact step at ts: candidate order =
      // (value-bits desc, beam asc, char asc) == flattened top_k tie rule
      const int row4 = (base + ts) * 4;
      float v[4]; int ci[4]; double lpk4[4], pk4[4];
      for (int k = 0; k < 4; ++k) {
        v[k] = d_t4v[row4 + k];
        ci[k] = d_t4i[row4 + k];
        lpk4[k] = d_t4lp[row4 + k];
        pk4[k] = d_t4p[row4 + k];
      }
      int sw[4], sc_[4], sk[4]; int ns = 0; int k = 0;
      while (ns < 4 && k < 4) {
        int k2 = k;
        while (k2 + 1 < 4 &&
               __float_as_uint(v[k2 + 1]) == __float_as_uint(v[k])) ++k2;
        for (int w = 0; w < 4 && ns < 4; ++w)
          for (int kk = k; kk <= k2 && ns < 4; ++kk) {
            sw[ns] = w; sc_[ns] = ci[kk]; sk[ns] = kk; ++ns;
          }
        k = k2 + 1;
      }
      double nl[4];
      for (int j = 0; j < 4; ++j) nl[j] = logs[sw[j]] + lpk4[sk[j]];
      int ord[4] = {0, 1, 2, 3};
      for (int a = 1; a < 4; ++a) {
        int o = ord[a]; int bb = a;
        while (bb > 0 && nl[ord[bb - 1]] < nl[o]) { ord[bb] = ord[bb - 1]; --bb; }
        ord[bb] = o;
      }
      for (int j = 0; j < 4; ++j) {
        Pst[ts][j] = sw[ord[j]];
        Chst[ts][j] = sc_[ord[j]];
      }
      double tl[4];
      for (int j = 0; j < 4; ++j) tl[j] = nl[ord[j]];
      for (int j = 0; j < 4; ++j) logs[j] = tl[j];
      if (ts == T_ - 1)
        for (int j = 0; j < 4; ++j) scor[j] = pk4[sk[ord[j]]];
      tprev = ts;
      lastSlow = ts;
    }
    double add = S[T_ - 1] - S[tprev];
    for (int j = 0; j < 4; ++j) logs[j] += add;
    if (lastSlow != T_ - 1)
      for (int j = 0; j < 4; ++j) scor[j] = p0v[T_ - 1];

    // final stable sort by f32-cast scores, desc (matches argsort(-scores))
    float sf[4];
    for (int j = 0; j < 4; ++j) sf[j] = (float)scor[j];
    int ford[4] = {0, 1, 2, 3};
    for (int a = 1; a < 4; ++a) {
      int o = ford[a]; int bb = a;
      while (bb > 0 && sf[ford[bb - 1]] < sf[o]) { ford[bb] = ford[bb - 1]; --bb; }
      ford[bb] = o;
    }
    for (int w = 0; w < 4; ++w) {
      sh_ford[w] = ford[w];
      sh_scores[w] = scor[ford[w]];
      sh_logs[w] = logs[ford[w]];
    }
  }
  __syncthreads();

  // lanes 0..3: walk tie steps (descending) to resolve beam-dependent chars
  if (tid < W_) {
    int j = sh_ford[tid];
    unsigned long long mm = mask1;
    int phase = 1;
    while (true) {
      if (mm == 0) {
        if (phase == 1) { mm = mask0; phase = 0; continue; }
        break;
      }
      int bpos = 63 - __builtin_clzll(mm); mm &= ~(1ull << bpos);
      int ts = bpos + (phase ? 64 : 0);
      seq[tid][ts] = Chst[ts][j];
      j = Pst[ts][j];
    }
    seq[tid][0] = d_t4i[base * 4 + j];  // t=0 char of surviving seed index
  }
  __syncthreads();

  // outputs: seqs [B][W][T+1], scores [B][W], logs [B][W]
  for (int e = tid; e < W_ * (T_ + 1); e += 64) {
    int w = e / (T_ + 1), p = e % (T_ + 1);
    int c = (p == 0) ? 0 : seq[w][p - 1];
    if (c == 1) c = 0;  // EOS -> BLANK
    out[(size_t)(b * W_ + w) * (T_ + 1) + p] = (float)c;
  }
  if (tid < W_) {
    out[B_ * W_ * (T_ + 1) + b * W_ + tid] = (float)sh_scores[tid];
    out[B_ * W_ * (T_ + 1) + B_ * W_ + b * W_ + tid] = (float)sh_logs[tid];
  }
}

// ---------------------------------------------------------------------------
extern "C" void kernel_launch(void* const* d_in, const int* in_sizes, int n_in,
                              void* d_out, int out_size, void* d_ws,
                              size_t ws_size, hipStream_t stream) {
  const float* logits = (const float*)d_in[0];
  // d_in[1] = seq_len (all == T): unused by the reference math.

  char* ws = (char*)d_ws;
  double* d_lp0 = (double*)(ws + 0);        // 1024 f64 =  8 KB
  double* d_p0 = (double*)(ws + 8192);      // 1024 f64 =  8 KB
  double* d_t4lp = (double*)(ws + 16384);   // 4096 f64 = 32 KB
  double* d_t4p = (double*)(ws + 49152);    // 4096 f64 = 32 KB
  int* d_ci0 = (int*)(ws + 81920);          // 1024 i32 =  4 KB
  int* d_tied = (int*)(ws + 86016);         // 1024 i32 =  4 KB
  float* d_t4v = (float*)(ws + 90112);      // 4096 f32 = 16 KB
  int* d_t4i = (int*)(ws + 106496);         // 4096 i32 = 16 KB
  float* out = (float*)d_out;

  hipLaunchKernelGGL(rowstats, dim3(NROWS), dim3(512), 0, stream,
                     logits, d_lp0, d_p0, d_ci0, d_tied,
                     d_t4v, d_t4i, d_t4lp, d_t4p);
  hipLaunchKernelGGL(beam_sim, dim3(B_), dim3(64), 0, stream,
                     d_lp0, d_p0, d_ci0, d_tied,
                     d_t4v, d_t4i, d_t4lp, d_t4p, out);
}